// Round 12
// baseline (337.423 us; speedup 1.0000x reference)
//
#include <hip/hip_runtime.h>
#include <hip/hip_bf16.h>
#include <hip/hip_cooperative_groups.h>
#include <stdint.h>

namespace cg = cooperative_groups;

// Problem constants (fixed by the reference).
#define M_DIM 8192
#define K_DIM 2048
#define N_DIM 2048

typedef __attribute__((ext_vector_type(8))) short bf16x8;
typedef __attribute__((ext_vector_type(4))) float f32x4;

// fp32 -> bf16 round-to-nearest-even (data has no NaNs).
__device__ __forceinline__ ushort f2bf(float f) {
    union { float f; uint32_t u; } v; v.f = f;
    uint32_t u = v.u;
    uint32_t r = u + 0x7fffu + ((u >> 16) & 1u);
    return (ushort)(r >> 16);
}

typedef const __attribute__((address_space(1))) uint32_t gu32;
typedef __attribute__((address_space(3))) uint32_t lu32;
__device__ __forceinline__ void load_lds16(const void* g, void* l) {
    // 16B per lane, dest = wave-uniform LDS base + lane*16 (HW rule).
    __builtin_amdgcn_global_load_lds((gu32*)g, (lu32*)l, 16, 0, 0);
}

// Workspace images are byte-for-byte LDS images (XOR-swizzled):
//   A image: per tile (rb*32+kt), 8KB: byte(r,k2) = r*128 + (k2 ^ ((r&7)<<4))
//   B image: per kt, 256KB: byte(n,k2) = n*128 + (k2 ^ ((n&7)<<4))

// =========================================================================
// FUSED cooperative kernel: 1024 blocks, 4 blocks/CU (launch_bounds(256,4)),
// 24KB LDS. Phase 1: block b scans 4 A-tiles (rb=b>>3, seg=b&7) AND converts
// one B tile (c=b). Phase 2: grid-stride 2048 gemm tiles, 2 per block.
// =========================================================================
__global__ __launch_bounds__(256, 4) void fused(const float* __restrict__ A,
                                                const float* __restrict__ B,
                                                char* __restrict__ Btk,
                                                char* __restrict__ Abf,
                                                uint8_t* __restrict__ maskb,
                                                float* __restrict__ C) {
    __shared__ __align__(16) char smem[24576];
    const int b = blockIdx.x;
    const int t = threadIdx.x;

    // ---- Phase 1a: scan 4 A-tiles (cols seg*256 .. seg*256+255), pipelined ----
    {
        const int rb = b >> 3;            // 0..127
        const int seg = b & 7;            // 0..7
        const int r  = t >> 2;            // row in tile 0..63
        const int cs = (t & 3) << 2;      // float col base {0,4,8,12}; +i*16
        const float* base = A + (size_t)(rb * 64 + r) * K_DIM + seg * 256 + cs;
        const int sw = (r & 7) << 4;
        float4 cur[4], nxt[4];
#pragma unroll
        for (int i = 0; i < 4; ++i) cur[i] = *(const float4*)(base + i * 16);
#pragma unroll
        for (int it = 0; it < 4; ++it) {
            if (it < 3) {
#pragma unroll
                for (int i = 0; i < 4; ++i)
                    nxt[i] = *(const float4*)(base + (it + 1) * 64 + i * 16);
            }
            bool nz = false;
#pragma unroll
            for (int i = 0; i < 4; ++i)
                nz = nz || (cur[i].x != 0.f) || (cur[i].y != 0.f) ||
                           (cur[i].z != 0.f) || (cur[i].w != 0.f);
            const int anynz = __syncthreads_or((int)nz);
            const int kt = seg * 4 + it;
            if (anynz) {
                char* dst = Abf + (size_t)(rb * 32 + kt) * 8192 + r * 128;
#pragma unroll
                for (int i = 0; i < 4; ++i) {
                    uint32_t lo = (uint32_t)f2bf(cur[i].x) | ((uint32_t)f2bf(cur[i].y) << 16);
                    uint32_t hi = (uint32_t)f2bf(cur[i].z) | ((uint32_t)f2bf(cur[i].w) << 16);
                    *(uint2*)(dst + ((cs * 2 + i * 32) ^ sw)) = make_uint2(lo, hi);
                }
            }
            if (t == 0) maskb[rb * 32 + kt] = anynz ? 1 : 0;
#pragma unroll
            for (int i = 0; i < 4; ++i) cur[i] = nxt[i];
        }
    }

    // ---- Phase 1b: convert one 64x64 B tile -> swizzled k-tile-major image ----
    {
        ushort(*lds)[70] = (ushort(*)[70])smem;
        const int c = b;
        const int c0 = (c & 31) * 64;     // N offset
        const int r0 = (c >> 5) * 64;     // K offset
        const int kt = r0 >> 6;
        const int r  = t >> 2;
        const int cs = (t & 3) << 2;
        __syncthreads();                  // reuse smem after scan's barriers
#pragma unroll
        for (int i = 0; i < 4; ++i) {
            int cc = cs + i * 16;
            float4 v = *(const float4*)(B + (size_t)(r0 + r) * N_DIM + c0 + cc);
            lds[r][cc + 0] = f2bf(v.x);
            lds[r][cc + 1] = f2bf(v.y);
            lds[r][cc + 2] = f2bf(v.z);
            lds[r][cc + 3] = f2bf(v.w);
        }
        __syncthreads();
        const int ct = t >> 2;            // n within tile, 0..63
        const int s  = (t & 3) * 16;      // k segment base
        uint4 tmpv[2];
        ushort* tmp = (ushort*)tmpv;
#pragma unroll
        for (int j = 0; j < 16; ++j) tmp[j] = lds[s + j][ct];
        const int n = c0 + ct;
        char* dst = Btk + (size_t)kt * 262144 + (size_t)n * 128;
        const int swn = (n & 7) << 4;
        *(uint4*)(dst + ((s * 2)      ^ swn)) = tmpv[0];
        *(uint4*)(dst + ((s * 2 + 16) ^ swn)) = tmpv[1];
    }

    // Release phase-1 writes, grid barrier, acquire (L2 invalidate).
    __threadfence();
    cg::this_grid().sync();
    __threadfence();

    // ================= Phase 2: block-sparse GEMM, 2 tiles/block =================
    char* sA = smem;              // [row 64][k 64] bf16, swizzled (8KB)
    char* sB = smem + 8192;       // [n 128][k 64]  bf16, swizzled (16KB)
    const int lane = t & 63;
    const int wid = t >> 6;
    const int wm = wid >> 1;      // 0..1
    const int wn = wid & 1;       // 0..1

    for (int g = b; g < 2048; g += 1024) {
        const int xcd = g & 7;                  // 1024 % 8 == 0: property preserved
        const int i0 = g >> 3;                  // 0..255
        const int cb = xcd * 2 + (i0 & 1);      // 0..15
        const int rb = i0 >> 1;                 // 0..127

        __syncthreads();   // smem reuse: phase-1 / prior epilogue vs new staging

        f32x4 acc[2][4];
#pragma unroll
        for (int i = 0; i < 2; ++i)
#pragma unroll
            for (int j = 0; j < 4; ++j) acc[i][j] = (f32x4){0.f, 0.f, 0.f, 0.f};

        const uint8_t* mb = maskb + rb * 32;
        uint32_t m = 0;
#pragma unroll
        for (int i = 0; i < 32; ++i) m |= (mb[i] ? 1u : 0u) << i;

        while (m) {
            const int kt = __ffs((int)m) - 1;
            m &= (m - 1);
            {
                const char* bt = Btk + (size_t)kt * 262144 + (size_t)cb * 16384;
#pragma unroll
                for (int i = 0; i < 4; ++i) {
                    const int chunk = wid * 4 + i;              // 0..15, 1KB each
                    load_lds16(bt + chunk * 1024 + lane * 16, sB + chunk * 1024);
                }
            }
            {
                const char* at = Abf + (size_t)(rb * 32 + kt) * 8192;
#pragma unroll
                for (int i = 0; i < 2; ++i) {
                    const int chunk = wid * 2 + i;              // 0..7, 1KB each
                    load_lds16(at + chunk * 1024 + lane * 16, sA + chunk * 1024);
                }
            }
            __syncthreads();

#pragma unroll
            for (int ks = 0; ks < 2; ++ks) {
                bf16x8 af[2], bfr[4];
#pragma unroll
                for (int mf = 0; mf < 2; ++mf) {
                    int row = wm * 32 + mf * 16 + (lane & 15);
                    int byte = row * 128 + (ks * 32 + (lane >> 4) * 8) * 2;
                    byte ^= ((row & 7) << 4);
                    af[mf] = *(const bf16x8*)(sA + byte);
                }
#pragma unroll
                for (int nf = 0; nf < 4; ++nf) {
                    int row = wn * 64 + nf * 16 + (lane & 15);
                    int byte = row * 128 + (ks * 32 + (lane >> 4) * 8) * 2;
                    byte ^= ((row & 7) << 4);
                    bfr[nf] = *(const bf16x8*)(sB + byte);
                }
#pragma unroll
                for (int mf = 0; mf < 2; ++mf)
#pragma unroll
                    for (int nf = 0; nf < 4; ++nf)
                        acc[mf][nf] = __builtin_amdgcn_mfma_f32_16x16x32_bf16(
                            af[mf], bfr[nf], acc[mf][nf], 0, 0, 0);
            }
            __syncthreads();
        }

        // epilogue: per-wave LDS transpose -> f32x4 nontemporal stores
        float* ep = (float*)(smem + wid * 4224);
        const int crow_base = rb * 64 + wm * 32;
        const int ccol_base = cb * 128 + wn * 64;
#pragma unroll
        for (int mf = 0; mf < 2; ++mf) {
#pragma unroll
            for (int nf = 0; nf < 4; ++nf)
#pragma unroll
                for (int j = 0; j < 4; ++j)
                    ep[((lane >> 4) * 4 + j) * 66 + nf * 16 + (lane & 15)] = acc[mf][nf][j];
#pragma unroll
            for (int rep = 0; rep < 4; ++rep) {
                int row16 = rep * 4 + (lane >> 4);
                f32x4 v = *(const f32x4*)(ep + row16 * 66 + (lane & 15) * 4);
                float* dst = C + (size_t)(crow_base + mf * 16 + row16) * N_DIM
                             + ccol_base + (lane & 15) * 4;
                __builtin_nontemporal_store(v, (f32x4*)dst);
            }
        }
    }
}

// =========================================================================
// FALLBACK: proven R9 two-kernel pair (41.0 us) — used if coop launch fails.
// =========================================================================
__global__ __launch_bounds__(256) void prep_fb(const float* __restrict__ A,
                                               const float* __restrict__ B,
                                               char* __restrict__ Btk,
                                               char* __restrict__ Abf,
                                               uint8_t* __restrict__ maskb) {
    __shared__ __align__(16) ushort lds[64][70];
    const int b = blockIdx.x;
    const int t = threadIdx.x;

    if (b < 512) {
        const int rb = b >> 2;
        const int seg = b & 3;
        const int r  = t >> 2;
        const int cs = (t & 3) << 2;
        const float* base = A + (size_t)(rb * 64 + r) * K_DIM + seg * 512 + cs;
        const int sw = (r & 7) << 4;
        uint32_t outb = 0;
        float4 cur[4], nxt[4];
#pragma unroll
        for (int i = 0; i < 4; ++i) cur[i] = *(const float4*)(base + i * 16);
#pragma unroll
        for (int it = 0; it < 8; ++it) {
            if (it < 7) {
#pragma unroll
                for (int i = 0; i < 4; ++i) nxt[i] = *(const float4*)(base + (it + 1) * 64 + i * 16);
            }
            bool nz = false;
#pragma unroll
            for (int i = 0; i < 4; ++i)
                nz = nz || (cur[i].x != 0.f) || (cur[i].y != 0.f) ||
                           (cur[i].z != 0.f) || (cur[i].w != 0.f);
            int anynz = __syncthreads_or((int)nz);
            const int kt = seg * 8 + it;
            if (anynz) {
                outb |= 1u;
                char* dst = Abf + (size_t)(rb * 32 + kt) * 8192 + r * 128;
#pragma unroll
                for (int i = 0; i < 4; ++i) {
                    uint32_t lo = (uint32_t)f2bf(cur[i].x) | ((uint32_t)f2bf(cur[i].y) << 16);
                    uint32_t hi = (uint32_t)f2bf(cur[i].z) | ((uint32_t)f2bf(cur[i].w) << 16);
                    *(uint2*)(dst + ((cs * 2 + i * 32) ^ sw)) = make_uint2(lo, hi);
                }
            }
            if (t == 0) maskb[rb * 32 + kt] = (uint8_t)(outb & 1);
            outb = 0;
#pragma unroll
            for (int i = 0; i < 4; ++i) cur[i] = nxt[i];
        }
    } else {
        const int c = b - 512;
        const int c0 = (c & 31) * 64;
        const int r0 = (c >> 5) * 64;
        const int kt = r0 >> 6;
        const int r  = t >> 2;
        const int cs = (t & 3) << 2;
#pragma unroll
        for (int i = 0; i < 4; ++i) {
            int cc = cs + i * 16;
            float4 v = *(const float4*)(B + (size_t)(r0 + r) * N_DIM + c0 + cc);
            lds[r][cc + 0] = f2bf(v.x);
            lds[r][cc + 1] = f2bf(v.y);
            lds[r][cc + 2] = f2bf(v.z);
            lds[r][cc + 3] = f2bf(v.w);
        }
        __syncthreads();
        const int ct = t >> 2;
        const int s  = (t & 3) * 16;
        uint4 tmpv[2];
        ushort* tmp = (ushort*)tmpv;
#pragma unroll
        for (int j = 0; j < 16; ++j) tmp[j] = lds[s + j][ct];
        const int n = c0 + ct;
        char* dst = Btk + (size_t)kt * 262144 + (size_t)n * 128;
        const int swn = (n & 7) << 4;
        *(uint4*)(dst + ((s * 2)      ^ swn)) = tmpv[0];
        *(uint4*)(dst + ((s * 2 + 16) ^ swn)) = tmpv[1];
    }
}

__global__ __launch_bounds__(256) void gemm_fb(const char* __restrict__ Abf,
                                               const char* __restrict__ Btk,
                                               const uint8_t* __restrict__ maskb,
                                               float* __restrict__ C) {
    __shared__ __align__(16) char smem[49152];   // dbuf: A0|A1|B0|B1

    const int orig = blockIdx.x;
    const int xcd = orig & 7;
    const int i0 = orig >> 3;
    const int cb = xcd * 2 + (i0 & 1);
    const int rb = i0 >> 1;
    const int tid = threadIdx.x;
    const int lane = tid & 63;
    const int wid = tid >> 6;
    const int wm = wid >> 1;
    const int wn = wid & 1;

    f32x4 acc[2][4];
#pragma unroll
    for (int i = 0; i < 2; ++i)
#pragma unroll
        for (int j = 0; j < 4; ++j) acc[i][j] = (f32x4){0.f, 0.f, 0.f, 0.f};

    const uint8_t* mb = maskb + rb * 32;
    uint32_t m = 0;
#pragma unroll
    for (int i = 0; i < 32; ++i) m |= (mb[i] ? 1u : 0u) << i;

#define STAGE_TILE(PBUF, KT)                                                     \
    do {                                                                         \
        const char* bt_ = Btk + (size_t)(KT) * 262144 + (size_t)cb * 16384;      \
        char* sBp_ = smem + 16384 + (PBUF) * 16384;                              \
        _Pragma("unroll")                                                        \
        for (int i_ = 0; i_ < 4; ++i_) {                                         \
            const int ch_ = wid * 4 + i_;                                        \
            load_lds16(bt_ + ch_ * 1024 + lane * 16, sBp_ + ch_ * 1024);         \
        }                                                                        \
        const char* at_ = Abf + (size_t)(rb * 32 + (KT)) * 8192;                 \
        char* sAp_ = smem + (PBUF) * 8192;                                       \
        _Pragma("unroll")                                                        \
        for (int i_ = 0; i_ < 2; ++i_) {                                         \
            const int ch_ = wid * 2 + i_;                                        \
            load_lds16(at_ + ch_ * 1024 + lane * 16, sAp_ + ch_ * 1024);         \
        }                                                                        \
    } while (0)

    if (m) {
        int kt = __ffs((int)m) - 1;
        m &= (m - 1);
        STAGE_TILE(0, kt);
        int p = 0;
        for (;;) {
            int ktn = -1;
            if (m) {
                ktn = __ffs((int)m) - 1;
                m &= (m - 1);
                STAGE_TILE(p ^ 1, ktn);
                asm volatile("s_waitcnt vmcnt(6)" ::: "memory");
            } else {
                asm volatile("s_waitcnt vmcnt(0)" ::: "memory");
            }
            __builtin_amdgcn_s_barrier();
            __builtin_amdgcn_sched_barrier(0);

            const char* sAp = smem + p * 8192;
            const char* sBp = smem + 16384 + p * 16384;
#pragma unroll
            for (int ks = 0; ks < 2; ++ks) {
                bf16x8 af[2], bfr[4];
#pragma unroll
                for (int mf = 0; mf < 2; ++mf) {
                    int row = wm * 32 + mf * 16 + (lane & 15);
                    int byte = row * 128 + (ks * 32 + (lane >> 4) * 8) * 2;
                    byte ^= ((row & 7) << 4);
                    af[mf] = *(const bf16x8*)(sAp + byte);
                }
#pragma unroll
                for (int nf = 0; nf < 4; ++nf) {
                    int row = wn * 64 + nf * 16 + (lane & 15);
                    int byte = row * 128 + (ks * 32 + (lane >> 4) * 8) * 2;
                    byte ^= ((row & 7) << 4);
                    bfr[nf] = *(const bf16x8*)(sBp + byte);
                }
#pragma unroll
                for (int mf = 0; mf < 2; ++mf)
#pragma unroll
                    for (int nf = 0; nf < 4; ++nf)
                        acc[mf][nf] = __builtin_amdgcn_mfma_f32_16x16x32_bf16(
                            af[mf], bfr[nf], acc[mf][nf], 0, 0, 0);
            }
            if (ktn < 0) break;
            __builtin_amdgcn_sched_barrier(0);
            __builtin_amdgcn_s_barrier();
            p ^= 1;
            kt = ktn;
        }
    }
#undef STAGE_TILE

    __syncthreads();

    float* ep = (float*)(smem + wid * 4224);
    const int crow_base = rb * 64 + wm * 32;
    const int ccol_base = cb * 128 + wn * 64;
#pragma unroll
    for (int mf = 0; mf < 2; ++mf) {
#pragma unroll
        for (int nf = 0; nf < 4; ++nf)
#pragma unroll
            for (int j = 0; j < 4; ++j)
                ep[((lane >> 4) * 4 + j) * 66 + nf * 16 + (lane & 15)] = acc[mf][nf][j];
#pragma unroll
        for (int rep = 0; rep < 4; ++rep) {
            int row16 = rep * 4 + (lane >> 4);
            f32x4 v = *(const f32x4*)(ep + row16 * 66 + (lane & 15) * 4);
            float* dst = C + (size_t)(crow_base + mf * 16 + row16) * N_DIM
                         + ccol_base + (lane & 15) * 4;
            __builtin_nontemporal_store(v, (f32x4*)dst);
        }
    }
}

extern "C" void kernel_launch(void* const* d_in, const int* in_sizes, int n_in,
                              void* d_out, int out_size, void* d_ws, size_t ws_size,
                              hipStream_t stream) {
    const float* A = (const float*)d_in[0];
    const float* B = (const float*)d_in[1];
    float* C = (float*)d_out;

    // Workspace: [0,8MB) Btk image; [8MB,40MB) Abf images (4096 tiles * 8KB);
    //            [40MB,+4KB) byte mask (one per tile)
    char* Btk = (char*)d_ws;
    char* Abf = (char*)d_ws + (size_t)8 * 1024 * 1024;
    uint8_t* maskb = (uint8_t*)((char*)d_ws + (size_t)40 * 1024 * 1024);

    void* args[] = {(void*)&A, (void*)&B, (void*)&Btk, (void*)&Abf,
                    (void*)&maskb, (void*)&C};
    hipError_t rc = hipLaunchCooperativeKernel((const void*)fused, dim3(1024),
                                               dim3(256), args, 0, stream);
    if (rc != hipSuccess) {
        (void)hipGetLastError();   // clear sticky error
        prep_fb<<<1536, 256, 0, stream>>>(A, B, Btk, Abf, maskb);
        gemm_fb<<<2048, 256, 0, stream>>>(Abf, Btk, maskb, C);
    }
}

// Round 13
// 56.245 us; speedup vs baseline: 5.9992x; 5.9992x over previous
//
#include <hip/hip_runtime.h>
#include <hip/hip_bf16.h>
#include <stdint.h>

// Problem constants (fixed by the reference).
#define M_DIM 8192
#define K_DIM 2048
#define N_DIM 2048

typedef __attribute__((ext_vector_type(8))) short bf16x8;
typedef __attribute__((ext_vector_type(4))) float f32x4;

// fp32 -> bf16 round-to-nearest-even (data has no NaNs).
__device__ __forceinline__ ushort f2bf(float f) {
    union { float f; uint32_t u; } v; v.f = f;
    uint32_t u = v.u;
    uint32_t r = u + 0x7fffu + ((u >> 16) & 1u);
    return (ushort)(r >> 16);
}

typedef const __attribute__((address_space(1))) uint32_t gu32;
typedef __attribute__((address_space(3))) uint32_t lu32;
__device__ __forceinline__ void load_lds16(const void* g, void* l) {
    // 16B per lane, dest = wave-uniform LDS base + lane*16 (HW rule).
    __builtin_amdgcn_global_load_lds((gu32*)g, (lu32*)l, 16, 0, 0);
}

// ===== R9 kernels, byte-identical (best measured: 41.0 us). This round's only
// change is in kernel_launch: prep is launched TWICE (idempotent) so the bench
// total reveals prep's duration: prep = dur(R13) - dur(R9). =====

__global__ __launch_bounds__(256) void prep(const float* __restrict__ A,
                                            const float* __restrict__ B,
                                            char* __restrict__ Btk,
                                            char* __restrict__ Abf,
                                            uint8_t* __restrict__ maskb) {
    __shared__ __align__(16) ushort lds[64][70];
    const int b = blockIdx.x;
    const int t = threadIdx.x;

    if (b < 512) {
        // ---- scan + pack: 8 k-tiles of one row-block quarter ----
        const int rb = b >> 2;
        const int seg = b & 3;
        const int r  = t >> 2;            // row in tile 0..63
        const int cs = (t & 3) << 2;      // float col base {0,4,8,12}; +i*16
        const float* base = A + (size_t)(rb * 64 + r) * K_DIM + seg * 512 + cs;
        const int sw = (r & 7) << 4;
        uint32_t outb = 0;
        float4 cur[4], nxt[4];
#pragma unroll
        for (int i = 0; i < 4; ++i) cur[i] = *(const float4*)(base + i * 16);
#pragma unroll
        for (int it = 0; it < 8; ++it) {
            if (it < 7) {
#pragma unroll
                for (int i = 0; i < 4; ++i) nxt[i] = *(const float4*)(base + (it + 1) * 64 + i * 16);
            }
            bool nz = false;
#pragma unroll
            for (int i = 0; i < 4; ++i)
                nz = nz || (cur[i].x != 0.f) || (cur[i].y != 0.f) ||
                           (cur[i].z != 0.f) || (cur[i].w != 0.f);
            int anynz = __syncthreads_or((int)nz);
            if (anynz) {
                outb |= 1u << it;
                char* dst = Abf + (size_t)(rb * 32 + seg * 8 + it) * 8192 + r * 128;
#pragma unroll
                for (int i = 0; i < 4; ++i) {
                    uint32_t lo = (uint32_t)f2bf(cur[i].x) | ((uint32_t)f2bf(cur[i].y) << 16);
                    uint32_t hi = (uint32_t)f2bf(cur[i].z) | ((uint32_t)f2bf(cur[i].w) << 16);
                    *(uint2*)(dst + ((cs * 2 + i * 32) ^ sw)) = make_uint2(lo, hi);
                }
            }
#pragma unroll
            for (int i = 0; i < 4; ++i) cur[i] = nxt[i];
        }
        if (t == 0) maskb[rb * 4 + seg] = (uint8_t)outb;
    } else {
        // ---- conv: one 64x64 tile of B -> swizzled k-tile-major image ----
        const int c = b - 512;
        const int c0 = (c & 31) * 64;     // N offset
        const int r0 = (c >> 5) * 64;     // K offset
        const int kt = r0 >> 6;
        const int r  = t >> 2;
        const int cs = (t & 3) << 2;
#pragma unroll
        for (int i = 0; i < 4; ++i) {
            int cc = cs + i * 16;
            float4 v = *(const float4*)(B + (size_t)(r0 + r) * N_DIM + c0 + cc);
            lds[r][cc + 0] = f2bf(v.x);
            lds[r][cc + 1] = f2bf(v.y);
            lds[r][cc + 2] = f2bf(v.z);
            lds[r][cc + 3] = f2bf(v.w);
        }
        __syncthreads();
        const int ct = t >> 2;            // n within tile, 0..63
        const int s  = (t & 3) * 16;      // k segment base
        uint4 tmpv[2];
        ushort* tmp = (ushort*)tmpv;
#pragma unroll
        for (int j = 0; j < 16; ++j) tmp[j] = lds[s + j][ct];
        const int n = c0 + ct;
        char* dst = Btk + (size_t)kt * 262144 + (size_t)n * 128;
        const int swn = (n & 7) << 4;
        *(uint4*)(dst + ((s * 2)      ^ swn)) = tmpv[0];
        *(uint4*)(dst + ((s * 2 + 16) ^ swn)) = tmpv[1];
    }
}

__global__ __launch_bounds__(256) void gemm_sparse(const char* __restrict__ Abf,
                                                   const char* __restrict__ Btk,
                                                   const uint32_t* __restrict__ mask,
                                                   float* __restrict__ C) {
    // layout: [A0 8K][A1 8K][B0 16K][B1 16K] = 48KB; epilogue reuses [0,16.9K)
    __shared__ __align__(16) char smem[49152];

    const int orig = blockIdx.x;
    const int xcd = orig & 7;                 // assumes round-robin wg->XCD; perf-only
    const int i0 = orig >> 3;                 // 0..255
    const int cb = xcd * 2 + (i0 & 1);        // 0..15: fixed pair of cbs per XCD
    const int rb = i0 >> 1;                   // 0..127
    const int tid = threadIdx.x;
    const int lane = tid & 63;
    const int wid = tid >> 6;
    const int wm = wid >> 1;      // 0..1
    const int wn = wid & 1;       // 0..1

    f32x4 acc[2][4];
#pragma unroll
    for (int i = 0; i < 2; ++i)
#pragma unroll
        for (int j = 0; j < 4; ++j) acc[i][j] = (f32x4){0.f, 0.f, 0.f, 0.f};

    uint32_t m = mask[rb];

    // 6 vector loads per thread per tile (4 B-chunks + 2 A-chunks).
#define STAGE_TILE(PBUF, KT)                                                     \
    do {                                                                         \
        const char* bt_ = Btk + (size_t)(KT) * 262144 + (size_t)cb * 16384;      \
        char* sBp_ = smem + 16384 + (PBUF) * 16384;                              \
        _Pragma("unroll")                                                        \
        for (int i_ = 0; i_ < 4; ++i_) {                                         \
            const int ch_ = wid * 4 + i_;                                        \
            load_lds16(bt_ + ch_ * 1024 + lane * 16, sBp_ + ch_ * 1024);         \
        }                                                                        \
        const char* at_ = Abf + (size_t)(rb * 32 + (KT)) * 8192;                 \
        char* sAp_ = smem + (PBUF) * 8192;                                       \
        _Pragma("unroll")                                                        \
        for (int i_ = 0; i_ < 2; ++i_) {                                         \
            const int ch_ = wid * 2 + i_;                                        \
            load_lds16(at_ + ch_ * 1024 + lane * 16, sAp_ + ch_ * 1024);         \
        }                                                                        \
    } while (0)

    if (m) {
        int kt = __ffs((int)m) - 1;
        m &= (m - 1);
        STAGE_TILE(0, kt);
        int p = 0;
        for (;;) {
            int ktn = -1;
            if (m) {
                ktn = __ffs((int)m) - 1;
                m &= (m - 1);
                STAGE_TILE(p ^ 1, ktn);          // prefetch next tile (other buffer)
                asm volatile("s_waitcnt vmcnt(6)" ::: "memory");  // cur's 6 retired
            } else {
                asm volatile("s_waitcnt vmcnt(0)" ::: "memory");  // last tile: drain
            }
            __builtin_amdgcn_s_barrier();          // all threads' cur data in LDS
            __builtin_amdgcn_sched_barrier(0);     // pin ds_reads below barrier

            const char* sAp = smem + p * 8192;
            const char* sBp = smem + 16384 + p * 16384;
#pragma unroll
            for (int ks = 0; ks < 2; ++ks) {
                bf16x8 af[2], bfr[4];
#pragma unroll
                for (int mf = 0; mf < 2; ++mf) {
                    int row = wm * 32 + mf * 16 + (lane & 15);
                    int byte = row * 128 + (ks * 32 + (lane >> 4) * 8) * 2;
                    byte ^= ((row & 7) << 4);
                    af[mf] = *(const bf16x8*)(sAp + byte);
                }
#pragma unroll
                for (int nf = 0; nf < 4; ++nf) {
                    int row = wn * 64 + nf * 16 + (lane & 15);
                    int byte = row * 128 + (ks * 32 + (lane >> 4) * 8) * 2;
                    byte ^= ((row & 7) << 4);
                    bfr[nf] = *(const bf16x8*)(sBp + byte);
                }
#pragma unroll
                for (int mf = 0; mf < 2; ++mf)
#pragma unroll
                    for (int nf = 0; nf < 4; ++nf)
                        acc[mf][nf] = __builtin_amdgcn_mfma_f32_16x16x32_bf16(
                            af[mf], bfr[nf], acc[mf][nf], 0, 0, 0);
            }
            if (ktn < 0) break;
            __builtin_amdgcn_sched_barrier(0);
            __builtin_amdgcn_s_barrier();          // buf p consumed -> reusable
            p ^= 1;
            kt = ktn;
        }
    }
#undef STAGE_TILE

    __syncthreads();   // protect smem reuse by epilogue

    // ---- epilogue: per-wave LDS transpose -> f32x4 nontemporal stores ----
    float* ep = (float*)(smem + wid * 4224);
    const int crow_base = rb * 64 + wm * 32;
    const int ccol_base = cb * 128 + wn * 64;
#pragma unroll
    for (int mf = 0; mf < 2; ++mf) {
#pragma unroll
        for (int nf = 0; nf < 4; ++nf)
#pragma unroll
            for (int j = 0; j < 4; ++j)
                ep[((lane >> 4) * 4 + j) * 66 + nf * 16 + (lane & 15)] = acc[mf][nf][j];
#pragma unroll
        for (int rep = 0; rep < 4; ++rep) {
            int row16 = rep * 4 + (lane >> 4);
            f32x4 v = *(const f32x4*)(ep + row16 * 66 + (lane & 15) * 4);
            float* dst = C + (size_t)(crow_base + mf * 16 + row16) * N_DIM
                         + ccol_base + (lane & 15) * 4;
            __builtin_nontemporal_store(v, (f32x4*)dst);
        }
    }
}

extern "C" void kernel_launch(void* const* d_in, const int* in_sizes, int n_in,
                              void* d_out, int out_size, void* d_ws, size_t ws_size,
                              hipStream_t stream) {
    const float* A = (const float*)d_in[0];
    const float* B = (const float*)d_in[1];
    float* C = (float*)d_out;

    // Workspace: [0,8MB) Btk image; [8MB,40MB) Abf images (4096 tiles * 8KB);
    //            [40MB,+512) mask (128 x 4 bytes)
    char* Btk = (char*)d_ws;
    char* Abf = (char*)d_ws + (size_t)8 * 1024 * 1024;
    uint8_t* maskb = (uint8_t*)((char*)d_ws + (size_t)40 * 1024 * 1024);

    // MEASUREMENT ROUND: prep launched twice (idempotent — pure function of
    // A,B). dur(R13) - dur(R9) = prep duration. Deterministic output.
    prep<<<1536, 256, 0, stream>>>(A, B, Btk, Abf, maskb);
    prep<<<1536, 256, 0, stream>>>(A, B, Btk, Abf, maskb);
    gemm_sparse<<<(M_DIM / 64) * (N_DIM / 128), 256, 0, stream>>>(
        Abf, Btk, (const uint32_t*)maskb, C);
}

// Round 14
// 39.539 us; speedup vs baseline: 8.5339x; 1.4225x over previous
//
#include <hip/hip_runtime.h>
#include <hip/hip_bf16.h>
#include <stdint.h>

// Problem constants (fixed by the reference).
#define M_DIM 8192
#define K_DIM 2048
#define N_DIM 2048

typedef __attribute__((ext_vector_type(8))) short bf16x8;
typedef __attribute__((ext_vector_type(4))) float f32x4;

// fp32 -> bf16 round-to-nearest-even (data has no NaNs).
__device__ __forceinline__ ushort f2bf(float f) {
    union { float f; uint32_t u; } v; v.f = f;
    uint32_t u = v.u;
    uint32_t r = u + 0x7fffu + ((u >> 16) & 1u);
    return (ushort)(r >> 16);
}

typedef const __attribute__((address_space(1))) uint32_t gu32;
typedef __attribute__((address_space(3))) uint32_t lu32;
__device__ __forceinline__ void load_lds16(const void* g, void* l) {
    // 16B per lane, dest = wave-uniform LDS base + lane*16 (HW rule).
    __builtin_amdgcn_global_load_lds((gu32*)g, (lu32*)l, 16, 0, 0);
}

// Workspace images are byte-for-byte LDS images (XOR-swizzled):
//   A image: per tile (rb*32+kt), 8KB: byte(r,k2) = r*128 + (k2 ^ ((r&7)<<4))
//   B image: per kt, 256KB: byte(n,k2) = n*128 + (k2 ^ ((n&7)<<4))
//
// prep: byte-identical to R9 (measured ~15 us, ~2 us above traffic floor).
__global__ __launch_bounds__(256) void prep(const float* __restrict__ A,
                                            const float* __restrict__ B,
                                            char* __restrict__ Btk,
                                            char* __restrict__ Abf,
                                            uint8_t* __restrict__ maskb) {
    __shared__ __align__(16) ushort lds[64][70];
    const int b = blockIdx.x;
    const int t = threadIdx.x;

    if (b < 512) {
        // ---- scan + pack: 8 k-tiles of one row-block quarter ----
        const int rb = b >> 2;
        const int seg = b & 3;
        const int r  = t >> 2;            // row in tile 0..63
        const int cs = (t & 3) << 2;      // float col base {0,4,8,12}; +i*16
        const float* base = A + (size_t)(rb * 64 + r) * K_DIM + seg * 512 + cs;
        const int sw = (r & 7) << 4;
        uint32_t outb = 0;
        float4 cur[4], nxt[4];
#pragma unroll
        for (int i = 0; i < 4; ++i) cur[i] = *(const float4*)(base + i * 16);
#pragma unroll
        for (int it = 0; it < 8; ++it) {
            if (it < 7) {
#pragma unroll
                for (int i = 0; i < 4; ++i) nxt[i] = *(const float4*)(base + (it + 1) * 64 + i * 16);
            }
            bool nz = false;
#pragma unroll
            for (int i = 0; i < 4; ++i)
                nz = nz || (cur[i].x != 0.f) || (cur[i].y != 0.f) ||
                           (cur[i].z != 0.f) || (cur[i].w != 0.f);
            int anynz = __syncthreads_or((int)nz);
            if (anynz) {
                outb |= 1u << it;
                char* dst = Abf + (size_t)(rb * 32 + seg * 8 + it) * 8192 + r * 128;
#pragma unroll
                for (int i = 0; i < 4; ++i) {
                    uint32_t lo = (uint32_t)f2bf(cur[i].x) | ((uint32_t)f2bf(cur[i].y) << 16);
                    uint32_t hi = (uint32_t)f2bf(cur[i].z) | ((uint32_t)f2bf(cur[i].w) << 16);
                    *(uint2*)(dst + ((cs * 2 + i * 32) ^ sw)) = make_uint2(lo, hi);
                }
            }
#pragma unroll
            for (int i = 0; i < 4; ++i) cur[i] = nxt[i];
        }
        if (t == 0) maskb[rb * 4 + seg] = (uint8_t)outb;
    } else {
        // ---- conv: one 64x64 tile of B -> swizzled k-tile-major image ----
        const int c = b - 512;
        const int c0 = (c & 31) * 64;     // N offset
        const int r0 = (c >> 5) * 64;     // K offset
        const int kt = r0 >> 6;
        const int r  = t >> 2;
        const int cs = (t & 3) << 2;
#pragma unroll
        for (int i = 0; i < 4; ++i) {
            int cc = cs + i * 16;
            float4 v = *(const float4*)(B + (size_t)(r0 + r) * N_DIM + c0 + cc);
            lds[r][cc + 0] = f2bf(v.x);
            lds[r][cc + 1] = f2bf(v.y);
            lds[r][cc + 2] = f2bf(v.z);
            lds[r][cc + 3] = f2bf(v.w);
        }
        __syncthreads();
        const int ct = t >> 2;            // n within tile, 0..63
        const int s  = (t & 3) * 16;      // k segment base
        uint4 tmpv[2];
        ushort* tmp = (ushort*)tmpv;
#pragma unroll
        for (int j = 0; j < 16; ++j) tmp[j] = lds[s + j][ct];
        const int n = c0 + ct;
        char* dst = Btk + (size_t)kt * 262144 + (size_t)n * 128;
        const int swn = (n & 7) << 4;
        *(uint4*)(dst + ((s * 2)      ^ swn)) = tmpv[0];
        *(uint4*)(dst + ((s * 2 + 16) ^ swn)) = tmpv[1];
    }
}

// Block-sparse GEMM, 64x64 output tile per block (4096 blocks, 16/CU sequential,
// ~5 blocks/CU resident at 32KB LDS): better epilogue/k-loop overlap across
// blocks and 2x the load-balance smoothing vs the 64x128 version (gemm measured
// 24 us vs ~12 us floor in R13 — slack is overlap, not traffic).
__global__ __launch_bounds__(256) void gemm_sparse(const char* __restrict__ Abf,
                                                   const char* __restrict__ Btk,
                                                   const uint32_t* __restrict__ mask,
                                                   float* __restrict__ C) {
    // [A0 8K][A1 8K][B0 8K][B1 8K] = 32KB; epilogue reuses [0,18.4K)
    __shared__ __align__(16) char smem[32768];

    const int orig = blockIdx.x;
    const int xcd = orig & 7;                 // round-robin wg->XCD assumption; perf-only
    const int i0 = orig >> 3;                 // 0..511
    const int cb = xcd * 4 + (i0 & 3);        // 0..31: fixed 4 cbs per XCD (1MB B L2-res)
    const int rb = i0 >> 2;                   // 0..127; 4 consecutive blocks share A tile
    const int tid = threadIdx.x;
    const int lane = tid & 63;
    const int wid = tid >> 6;
    const int wm = wid >> 1;      // 0..1
    const int wn = wid & 1;       // 0..1

    f32x4 acc[2][2];
#pragma unroll
    for (int i = 0; i < 2; ++i)
#pragma unroll
        for (int j = 0; j < 2; ++j) acc[i][j] = (f32x4){0.f, 0.f, 0.f, 0.f};

    uint32_t m = mask[rb];

    // 4 vector loads per thread per tile (2 B-chunks + 2 A-chunks).
#define STAGE_TILE(PBUF, KT)                                                     \
    do {                                                                         \
        const char* bt_ = Btk + (size_t)(KT) * 262144 + (size_t)cb * 8192;       \
        char* sBp_ = smem + 16384 + (PBUF) * 8192;                               \
        _Pragma("unroll")                                                        \
        for (int i_ = 0; i_ < 2; ++i_) {                                         \
            const int ch_ = wid * 2 + i_;                                        \
            load_lds16(bt_ + ch_ * 1024 + lane * 16, sBp_ + ch_ * 1024);         \
        }                                                                        \
        const char* at_ = Abf + (size_t)(rb * 32 + (KT)) * 8192;                 \
        char* sAp_ = smem + (PBUF) * 8192;                                       \
        _Pragma("unroll")                                                        \
        for (int i_ = 0; i_ < 2; ++i_) {                                         \
            const int ch_ = wid * 2 + i_;                                        \
            load_lds16(at_ + ch_ * 1024 + lane * 16, sAp_ + ch_ * 1024);         \
        }                                                                        \
    } while (0)

    if (m) {
        int kt = __ffs((int)m) - 1;
        m &= (m - 1);
        STAGE_TILE(0, kt);
        int p = 0;
        for (;;) {
            int ktn = -1;
            if (m) {
                ktn = __ffs((int)m) - 1;
                m &= (m - 1);
                STAGE_TILE(p ^ 1, ktn);          // prefetch next tile (other buffer)
                asm volatile("s_waitcnt vmcnt(4)" ::: "memory");  // cur's 4 retired
            } else {
                asm volatile("s_waitcnt vmcnt(0)" ::: "memory");  // last tile: drain
            }
            __builtin_amdgcn_s_barrier();          // all threads' cur data in LDS
            __builtin_amdgcn_sched_barrier(0);     // pin ds_reads below barrier

            const char* sAp = smem + p * 8192;
            const char* sBp = smem + 16384 + p * 8192;
#pragma unroll
            for (int ks = 0; ks < 2; ++ks) {
                bf16x8 af[2], bfr[2];
#pragma unroll
                for (int mf = 0; mf < 2; ++mf) {
                    int row = wm * 32 + mf * 16 + (lane & 15);
                    int byte = row * 128 + (ks * 32 + (lane >> 4) * 8) * 2;
                    byte ^= ((row & 7) << 4);
                    af[mf] = *(const bf16x8*)(sAp + byte);
                }
#pragma unroll
                for (int nf = 0; nf < 2; ++nf) {
                    int row = wn * 32 + nf * 16 + (lane & 15);
                    int byte = row * 128 + (ks * 32 + (lane >> 4) * 8) * 2;
                    byte ^= ((row & 7) << 4);
                    bfr[nf] = *(const bf16x8*)(sBp + byte);
                }
#pragma unroll
                for (int mf = 0; mf < 2; ++mf)
#pragma unroll
                    for (int nf = 0; nf < 2; ++nf)
                        acc[mf][nf] = __builtin_amdgcn_mfma_f32_16x16x32_bf16(
                            af[mf], bfr[nf], acc[mf][nf], 0, 0, 0);
            }
            if (ktn < 0) break;
            __builtin_amdgcn_sched_barrier(0);
            __builtin_amdgcn_s_barrier();          // buf p consumed -> reusable
            p ^= 1;
            kt = ktn;
        }
    }
#undef STAGE_TILE

    __syncthreads();   // protect smem reuse by epilogue

    // ---- epilogue: per-wave LDS transpose -> f32x4 nontemporal stores ----
    // MFMA C/D layout: col=lane&15, row=(lane>>4)*4+reg. Each wave owns a
    // 32x36-float region (4608B, 16B-aligned rows); per-wave regions.
    float* ep = (float*)(smem + wid * 4608);
    const int crow_base = rb * 64 + wm * 32;
    const int ccol_base = cb * 64 + wn * 32;
#pragma unroll
    for (int mf = 0; mf < 2; ++mf)
#pragma unroll
        for (int nf = 0; nf < 2; ++nf)
#pragma unroll
            for (int j = 0; j < 4; ++j)
                ep[(mf * 16 + (lane >> 4) * 4 + j) * 36 + nf * 16 + (lane & 15)] =
                    acc[mf][nf][j];
#pragma unroll
    for (int rep = 0; rep < 4; ++rep) {
        int row32 = rep * 8 + (lane >> 3);
        f32x4 v = *(const f32x4*)(ep + row32 * 36 + (lane & 7) * 4);
        float* dst = C + (size_t)(crow_base + row32) * N_DIM
                     + ccol_base + (lane & 7) * 4;
        __builtin_nontemporal_store(v, (f32x4*)dst);
    }
}

extern "C" void kernel_launch(void* const* d_in, const int* in_sizes, int n_in,
                              void* d_out, int out_size, void* d_ws, size_t ws_size,
                              hipStream_t stream) {
    const float* A = (const float*)d_in[0];
    const float* B = (const float*)d_in[1];
    float* C = (float*)d_out;

    // Workspace: [0,8MB) Btk image; [8MB,40MB) Abf images (4096 tiles * 8KB);
    //            [40MB,+512) mask (128 x 4 bytes)
    char* Btk = (char*)d_ws;
    char* Abf = (char*)d_ws + (size_t)8 * 1024 * 1024;
    uint8_t* maskb = (uint8_t*)((char*)d_ws + (size_t)40 * 1024 * 1024);

    prep<<<1536, 256, 0, stream>>>(A, B, Btk, Abf, maskb);
    gemm_sparse<<<(M_DIM / 64) * (N_DIM / 64), 256, 0, stream>>>(
        Abf, Btk, (const uint32_t*)maskb, C);
}

// Round 15
// 38.998 us; speedup vs baseline: 8.6523x; 1.0139x over previous
//
#include <hip/hip_runtime.h>
#include <hip/hip_bf16.h>
#include <stdint.h>

// Problem constants (fixed by the reference).
#define M_DIM 8192
#define K_DIM 2048
#define N_DIM 2048

typedef __attribute__((ext_vector_type(8))) short bf16x8;
typedef __attribute__((ext_vector_type(4))) float f32x4;

// fp32 -> bf16 round-to-nearest-even (data has no NaNs).
__device__ __forceinline__ ushort f2bf(float f) {
    union { float f; uint32_t u; } v; v.f = f;
    uint32_t u = v.u;
    uint32_t r = u + 0x7fffu + ((u >> 16) & 1u);
    return (ushort)(r >> 16);
}

typedef const __attribute__((address_space(1))) uint32_t gu32;
typedef __attribute__((address_space(3))) uint32_t lu32;
__device__ __forceinline__ void load_lds16(const void* g, void* l) {
    // 16B per lane, dest = wave-uniform LDS base + lane*16 (HW rule).
    __builtin_amdgcn_global_load_lds((gu32*)g, (lu32*)l, 16, 0, 0);
}

// Workspace images are byte-for-byte LDS images (XOR-swizzled):
//   A image: per tile (rb*32+kt), 8KB: byte(r,k2) = r*128 + (k2 ^ ((r&7)<<4))
//   B image: per kt, 256KB: byte(n,k2) = n*128 + (k2 ^ ((n&7)<<4))
//
// prep: byte-identical to R9 (measured ~15 us, ~2 us above traffic floor).
__global__ __launch_bounds__(256) void prep(const float* __restrict__ A,
                                            const float* __restrict__ B,
                                            char* __restrict__ Btk,
                                            char* __restrict__ Abf,
                                            uint8_t* __restrict__ maskb) {
    __shared__ __align__(16) ushort lds[64][70];
    const int b = blockIdx.x;
    const int t = threadIdx.x;

    if (b < 512) {
        // ---- scan + pack: 8 k-tiles of one row-block quarter ----
        const int rb = b >> 2;
        const int seg = b & 3;
        const int r  = t >> 2;            // row in tile 0..63
        const int cs = (t & 3) << 2;      // float col base {0,4,8,12}; +i*16
        const float* base = A + (size_t)(rb * 64 + r) * K_DIM + seg * 512 + cs;
        const int sw = (r & 7) << 4;
        uint32_t outb = 0;
        float4 cur[4], nxt[4];
#pragma unroll
        for (int i = 0; i < 4; ++i) cur[i] = *(const float4*)(base + i * 16);
#pragma unroll
        for (int it = 0; it < 8; ++it) {
            if (it < 7) {
#pragma unroll
                for (int i = 0; i < 4; ++i) nxt[i] = *(const float4*)(base + (it + 1) * 64 + i * 16);
            }
            bool nz = false;
#pragma unroll
            for (int i = 0; i < 4; ++i)
                nz = nz || (cur[i].x != 0.f) || (cur[i].y != 0.f) ||
                           (cur[i].z != 0.f) || (cur[i].w != 0.f);
            int anynz = __syncthreads_or((int)nz);
            if (anynz) {
                outb |= 1u << it;
                char* dst = Abf + (size_t)(rb * 32 + seg * 8 + it) * 8192 + r * 128;
#pragma unroll
                for (int i = 0; i < 4; ++i) {
                    uint32_t lo = (uint32_t)f2bf(cur[i].x) | ((uint32_t)f2bf(cur[i].y) << 16);
                    uint32_t hi = (uint32_t)f2bf(cur[i].z) | ((uint32_t)f2bf(cur[i].w) << 16);
                    *(uint2*)(dst + ((cs * 2 + i * 32) ^ sw)) = make_uint2(lo, hi);
                }
            }
#pragma unroll
            for (int i = 0; i < 4; ++i) cur[i] = nxt[i];
        }
        if (t == 0) maskb[rb * 4 + seg] = (uint8_t)outb;
    } else {
        // ---- conv: one 64x64 tile of B -> swizzled k-tile-major image ----
        const int c = b - 512;
        const int c0 = (c & 31) * 64;     // N offset
        const int r0 = (c >> 5) * 64;     // K offset
        const int kt = r0 >> 6;
        const int r  = t >> 2;
        const int cs = (t & 3) << 2;
#pragma unroll
        for (int i = 0; i < 4; ++i) {
            int cc = cs + i * 16;
            float4 v = *(const float4*)(B + (size_t)(r0 + r) * N_DIM + c0 + cc);
            lds[r][cc + 0] = f2bf(v.x);
            lds[r][cc + 1] = f2bf(v.y);
            lds[r][cc + 2] = f2bf(v.z);
            lds[r][cc + 3] = f2bf(v.w);
        }
        __syncthreads();
        const int ct = t >> 2;            // n within tile, 0..63
        const int s  = (t & 3) * 16;      // k segment base
        uint4 tmpv[2];
        ushort* tmp = (ushort*)tmpv;
#pragma unroll
        for (int j = 0; j < 16; ++j) tmp[j] = lds[s + j][ct];
        const int n = c0 + ct;
        char* dst = Btk + (size_t)kt * 262144 + (size_t)n * 128;
        const int swn = (n & 7) << 4;
        *(uint4*)(dst + ((s * 2)      ^ swn)) = tmpv[0];
        *(uint4*)(dst + ((s * 2 + 16) ^ swn)) = tmpv[1];
    }
}

// Block-sparse GEMM, 64x64 tile, SINGLE-buffered 16KB LDS -> 8 blocks/CU
// (wave-slot cap) for latency hiding via TLP instead of double-buffering.
// R13 measurement: gemm ~23us vs ~12us traffic floor => latency-chain bound;
// R14 (dbuf, 5 blocks/CU) = 39.5us total. This trades pipeline depth for
// +60% co-resident blocks.
__global__ __launch_bounds__(256) void gemm_sparse(const char* __restrict__ Abf,
                                                   const char* __restrict__ Btk,
                                                   const uint32_t* __restrict__ mask,
                                                   float* __restrict__ C) {
    // [sA 8K][sB 8K] = 16KB; epilogue reuses [0, 9216) as 4 x 2304B wave regions
    __shared__ __align__(16) char smem[16384];
    char* sA = smem;
    char* sB = smem + 8192;

    const int orig = blockIdx.x;
    const int xcd = orig & 7;                 // round-robin wg->XCD assumption; perf-only
    const int i0 = orig >> 3;                 // 0..511
    const int cb = xcd * 4 + (i0 & 3);        // 0..31: fixed 4 cbs per XCD (1MB B L2-res)
    const int rb = i0 >> 2;                   // 0..127; 4 consecutive blocks share A tile
    const int tid = threadIdx.x;
    const int lane = tid & 63;
    const int wid = tid >> 6;
    const int wm = wid >> 1;      // 0..1
    const int wn = wid & 1;       // 0..1

    f32x4 acc[2][2];
#pragma unroll
    for (int i = 0; i < 2; ++i)
#pragma unroll
        for (int j = 0; j < 2; ++j) acc[i][j] = (f32x4){0.f, 0.f, 0.f, 0.f};

    uint32_t m = mask[rb];

    while (m) {
        const int kt = __ffs((int)m) - 1;
        m &= (m - 1);

        // stage B half-panel (8KB) + A tile (8KB): 4 linear gload_lds per thread
        {
            const char* bt = Btk + (size_t)kt * 262144 + (size_t)cb * 8192;
#pragma unroll
            for (int i = 0; i < 2; ++i) {
                const int ch = wid * 2 + i;                 // 0..7, 1KB each
                load_lds16(bt + ch * 1024 + lane * 16, sB + ch * 1024);
            }
            const char* at = Abf + (size_t)(rb * 32 + kt) * 8192;
#pragma unroll
            for (int i = 0; i < 2; ++i) {
                const int ch = wid * 2 + i;
                load_lds16(at + ch * 1024 + lane * 16, sA + ch * 1024);
            }
        }
        __syncthreads();    // drains vmcnt -> staged data visible to all waves

#pragma unroll
        for (int ks = 0; ks < 2; ++ks) {
            bf16x8 af[2], bfr[2];
#pragma unroll
            for (int mf = 0; mf < 2; ++mf) {
                int row = wm * 32 + mf * 16 + (lane & 15);
                int byte = row * 128 + (ks * 32 + (lane >> 4) * 8) * 2;
                byte ^= ((row & 7) << 4);
                af[mf] = *(const bf16x8*)(sA + byte);
            }
#pragma unroll
            for (int nf = 0; nf < 2; ++nf) {
                int row = wn * 32 + nf * 16 + (lane & 15);
                int byte = row * 128 + (ks * 32 + (lane >> 4) * 8) * 2;
                byte ^= ((row & 7) << 4);
                bfr[nf] = *(const bf16x8*)(sB + byte);
            }
#pragma unroll
            for (int mf = 0; mf < 2; ++mf)
#pragma unroll
                for (int nf = 0; nf < 2; ++nf)
                    acc[mf][nf] = __builtin_amdgcn_mfma_f32_16x16x32_bf16(
                        af[mf], bfr[nf], acc[mf][nf], 0, 0, 0);
        }
        __syncthreads();    // buffer consumed -> safe to restage
    }

    // ---- epilogue: per-wave compact 2-pass LDS transpose -> f32x4 NT stores ----
    // MFMA C/D layout: col=lane&15, row=(lane>>4)*4+reg. Wave-private 16x36-float
    // region (2304B) reused across the two mf halves (DS pipe is in-order within
    // a wave, so the WAR on re-write is safe without a barrier).
    float* ep = (float*)(smem + wid * 2304);
    const int crow_base = rb * 64 + wm * 32;
    const int ccol_base = cb * 64 + wn * 32;
#pragma unroll
    for (int mf = 0; mf < 2; ++mf) {
#pragma unroll
        for (int nf = 0; nf < 2; ++nf)
#pragma unroll
            for (int j = 0; j < 4; ++j)
                ep[((lane >> 4) * 4 + j) * 36 + nf * 16 + (lane & 15)] = acc[mf][nf][j];
#pragma unroll
        for (int rep = 0; rep < 2; ++rep) {
            int row16 = rep * 8 + (lane >> 3);
            f32x4 v = *(const f32x4*)(ep + row16 * 36 + (lane & 7) * 4);
            float* dst = C + (size_t)(crow_base + mf * 16 + row16) * N_DIM
                         + ccol_base + (lane & 7) * 4;
            __builtin_nontemporal_store(v, (f32x4*)dst);
        }
    }
}

extern "C" void kernel_launch(void* const* d_in, const int* in_sizes, int n_in,
                              void* d_out, int out_size, void* d_ws, size_t ws_size,
                              hipStream_t stream) {
    const float* A = (const float*)d_in[0];
    const float* B = (const float*)d_in[1];
    float* C = (float*)d_out;

    // Workspace: [0,8MB) Btk image; [8MB,40MB) Abf images (4096 tiles * 8KB);
    //            [40MB,+512) mask (128 x 4 bytes)
    char* Btk = (char*)d_ws;
    char* Abf = (char*)d_ws + (size_t)8 * 1024 * 1024;
    uint8_t* maskb = (uint8_t*)((char*)d_ws + (size_t)40 * 1024 * 1024);

    prep<<<1536, 256, 0, stream>>>(A, B, Btk, Abf, maskb);
    gemm_sparse<<<(M_DIM / 64) * (N_DIM / 64), 256, 0, stream>>>(
        Abf, Btk, (const uint32_t*)maskb, C);
}